// Round 1
// baseline (186.256 us; speedup 1.0000x reference)
//
#include <hip/hip_runtime.h>
#include <math.h>

// Problem constants (B=2, T=2048, E=1024, H=16, S=64)
#define T_SEQ 2048
#define E_DIM 1024
#define NH    16
#define HS    64
#define NB    2
#define M_ROWS 4096

typedef __attribute__((ext_vector_type(8))) short bf16x8;
typedef __attribute__((ext_vector_type(4))) short bf16x4;
typedef __attribute__((ext_vector_type(4))) float f32x4;

#define AS1 __attribute__((address_space(1)))
#define AS3 __attribute__((address_space(3)))

#define LOG2E 1.4426950408889634f

// 16x16x16 bf16 MFMA (K=16): B-operand k-index (quad*4+j) matches the
// C-layout row index (quad*4+r) — QK^T's S^T accumulator feeds PV directly.
__device__ __forceinline__ f32x4 mfma16(bf16x4 a, bf16x4 b, f32x4 c) {
    return __builtin_amdgcn_mfma_f32_16x16x16bf16_1k(a, b, c, 0, 0, 0);
}

__device__ __forceinline__ ushort f2bf(float f) {
    union { float f; unsigned u; } c; c.f = f;
    unsigned r = c.u + 0x7fffu + ((c.u >> 16) & 1u);
    return (ushort)(r >> 16);
}
__device__ __forceinline__ ushort f2bf_trunc(float f) {
    union { float f; unsigned u; } c; c.f = f;
    return (ushort)(c.u >> 16);
}

__device__ __forceinline__ void load_lds16(const ushort* g, ushort* l) {
    // 16B per lane, LDS dest = wave-uniform base + lane*16 (HW behavior)
    __builtin_amdgcn_global_load_lds((const AS1 unsigned int*)g,
                                     (AS3 unsigned int*)l, 16, 0, 0);
}

// ---------------------------------------------------------------------------
// fp32 -> bf16 conversion for x and the four weight matrices.
// ---------------------------------------------------------------------------
__global__ __launch_bounds__(256) void cvt_all(
    const float* __restrict__ x,  const float* __restrict__ Wk,
    const float* __restrict__ Wq, const float* __restrict__ Wv,
    const float* __restrict__ Wu,
    ushort* __restrict__ xb,  ushort* __restrict__ Wkb,
    ushort* __restrict__ Wqb, ushort* __restrict__ Wvb,
    ushort* __restrict__ Wub)
{
    int i4 = blockIdx.x * 256 + threadIdx.x;   // 0 .. 2M-1 (float4 units)
    int region = i4 >> 18;
    const float* src; ushort* dst; int off;
    if      (region < 4)  { src = x;  dst = xb;  off = i4; }
    else if (region == 4) { src = Wk; dst = Wkb; off = i4 - (4 << 18); }
    else if (region == 5) { src = Wq; dst = Wqb; off = i4 - (5 << 18); }
    else if (region == 6) { src = Wv; dst = Wvb; off = i4 - (6 << 18); }
    else                  { src = Wu; dst = Wub; off = i4 - (7 << 18); }
    float4 v = *(const float4*)(src + (size_t)off * 4);
    ushort4 o; o.x = f2bf(v.x); o.y = f2bf(v.y); o.z = f2bf(v.z); o.w = f2bf(v.w);
    *(ushort4*)(dst + (size_t)off * 4) = o;
}

// ---------------------------------------------------------------------------
// bf16 MFMA GEMM core with DOUBLE-BUFFERED staging and ONE barrier per
// K-iteration. 128x128 tile, BK=32, 4 waves in 2x2, 16 MFMA/wave/iter.
// ---------------------------------------------------------------------------
__device__ __forceinline__ void gemm_core_db(
    const ushort* __restrict__ A, const ushort* __restrict__ W,
    int m0, int n0, ushort* As, ushort* Bs, f32x4 acc[4][4])
{
    const int tid  = threadIdx.x;
    const int lane = tid & 63, w = tid >> 6;
    const int quad = lane >> 4, l16 = lane & 15;
    const int wm = w & 1, wn = w >> 1;

    const int rl   = lane >> 2;                       // row-in-chunk 0..15
    const int gsw  = (lane & 3) ^ ((lane >> 3) & 3);  // swizzled global chunk
    const int fsw  = (l16 >> 1) & 3;                  // frag-read xor factor

    const f32x4 zero = {0.f, 0.f, 0.f, 0.f};
#pragma unroll
    for (int mt = 0; mt < 4; ++mt)
#pragma unroll
        for (int nt = 0; nt < 4; ++nt) acc[mt][nt] = zero;

    // initial stage into buffer 0
#pragma unroll
    for (int i = 0; i < 2; ++i) {
        int c = i * 4 + w;                 // chunk 0..7 (16 rows x 64B)
        int row = c * 16 + rl;
        load_lds16(A + (size_t)(m0 + row) * E_DIM + gsw * 8, As + c * 512);
        load_lds16(W + (size_t)(n0 + row) * E_DIM + gsw * 8, Bs + c * 512);
    }

    for (int k0 = 0; k0 < E_DIM; k0 += 32) {
        const int buf = (k0 >> 5) & 1;
        ushort* Ab = As + buf * 4096;
        ushort* Bb = Bs + buf * 4096;
        __syncthreads();   // own-wave vmcnt drained -> buf ready; syncs reuse
        if (k0 + 32 < E_DIM) {
            ushort* An = As + (buf ^ 1) * 4096;
            ushort* Bn = Bs + (buf ^ 1) * 4096;
#pragma unroll
            for (int i = 0; i < 2; ++i) {
                int c = i * 4 + w;
                int row = c * 16 + rl;
                load_lds16(A + (size_t)(m0 + row) * E_DIM + k0 + 32 + gsw * 8,
                           An + c * 512);
                load_lds16(W + (size_t)(n0 + row) * E_DIM + k0 + 32 + gsw * 8,
                           Bn + c * 512);
            }
        }
        bf16x8 af[4], bfr[4];
#pragma unroll
        for (int mt = 0; mt < 4; ++mt)
            af[mt] = *(const bf16x8*)(Ab + (wm * 64 + mt * 16 + l16) * 32
                                      + ((quad ^ fsw) * 8));
#pragma unroll
        for (int nt = 0; nt < 4; ++nt)
            bfr[nt] = *(const bf16x8*)(Bb + (wn * 64 + nt * 16 + l16) * 32
                                       + ((quad ^ fsw) * 8));
#pragma unroll
        for (int mt = 0; mt < 4; ++mt)
#pragma unroll
            for (int nt = 0; nt < 4; ++nt)
                acc[mt][nt] = __builtin_amdgcn_mfma_f32_16x16x32_bf16(
                    af[mt], bfr[nt], acc[mt][nt], 0, 0, 0);
    }
}

// ---------------------------------------------------------------------------
// QKV GEMM (z-grid) with fused epilogues:
//  z=0: K -> LN(kln) -> Kb
//  z=1: Q -> LN(qln) * 0.125*log2e -> Qb
//  z=2: V -> transposed store -> Vt [bh][d][t]
// ---------------------------------------------------------------------------
__global__ __launch_bounds__(256) void gemm_qkv(
    const ushort* __restrict__ A,
    const ushort* __restrict__ W0, const ushort* __restrict__ W1,
    const ushort* __restrict__ W2,
    ushort* __restrict__ Kb, ushort* __restrict__ Qb, ushort* __restrict__ Vt,
    const float* __restrict__ kw, const float* __restrict__ kbias,
    const float* __restrict__ qw, const float* __restrict__ qbias)
{
    __shared__ ushort As[2 * 128 * 32];   // 16 KB
    __shared__ ushort Bs[2 * 128 * 32];   // 16 KB
    const int z = blockIdx.z;
    const ushort* W = (z == 0) ? W0 : (z == 1) ? W1 : W2;
    const int m0 = blockIdx.y * 128, n0 = blockIdx.x * 128;
    f32x4 acc[4][4];
    gemm_core_db(A, W, m0, n0, As, Bs, acc);

    const int lane = threadIdx.x & 63, w = threadIdx.x >> 6;
    const int quad = lane >> 4, l16 = lane & 15;
    const int wm = w & 1, wn = w >> 1;
    const int row0 = m0 + wm * 64;
    const int col0 = n0 + wn * 64;

    if (z < 2) {
        ushort* C = z ? Qb : Kb;
        const float* lw = z ? qw : kw;
        const float* lb = z ? qbias : kbias;
        const float scale = z ? (0.125f * LOG2E) : 1.0f;
        float wv[4], bv_[4];
#pragma unroll
        for (int nt = 0; nt < 4; ++nt) {
            wv[nt]  = lw[nt * 16 + l16];
            bv_[nt] = lb[nt * 16 + l16];
        }
#pragma unroll
        for (int mt = 0; mt < 4; ++mt)
#pragma unroll
            for (int r = 0; r < 4; ++r) {
                float v[4], d[4];
#pragma unroll
                for (int nt = 0; nt < 4; ++nt) v[nt] = acc[mt][nt][r];
                float s = v[0] + v[1] + v[2] + v[3];
                s += __shfl_xor(s, 1); s += __shfl_xor(s, 2);
                s += __shfl_xor(s, 4); s += __shfl_xor(s, 8);
                float mu = s * (1.0f / 64.0f);
                float q2 = 0.f;
#pragma unroll
                for (int nt = 0; nt < 4; ++nt) { d[nt] = v[nt] - mu; q2 += d[nt] * d[nt]; }
                q2 += __shfl_xor(q2, 1); q2 += __shfl_xor(q2, 2);
                q2 += __shfl_xor(q2, 4); q2 += __shfl_xor(q2, 8);
                float rin = rsqrtf(q2 * (1.0f / 64.0f) + 1e-5f);
                int row = row0 + mt * 16 + quad * 4 + r;
#pragma unroll
                for (int nt = 0; nt < 4; ++nt)
                    C[(size_t)row * E_DIM + col0 + nt * 16 + l16] =
                        f2bf((d[nt] * rin * wv[nt] + bv_[nt]) * scale);
            }
    } else {
        // V: transposed store Vt[(b*NH+h)*64 + d][t]
        const int bidx = m0 >> 11;
        const int hh   = col0 >> 6;
        const int t0   = (m0 & 2047) + wm * 64;
#pragma unroll
        for (int mt = 0; mt < 4; ++mt)
#pragma unroll
            for (int nt = 0; nt < 4; ++nt) {
                ushort4 pk = make_ushort4(f2bf(acc[mt][nt][0]), f2bf(acc[mt][nt][1]),
                                          f2bf(acc[mt][nt][2]), f2bf(acc[mt][nt][3]));
                size_t off = ((size_t)(bidx * NH + hh) * 64 + nt * 16 + l16) * T_SEQ
                             + t0 + mt * 16 + quad * 4;
                *(ushort4*)(Vt + off) = pk;
            }
    }
}

// ---------------------------------------------------------------------------
// Output GEMM: 128x128 tiles (grid 8x32 = 256 blocks), dbuf core, fp32 store.
// ---------------------------------------------------------------------------
__global__ __launch_bounds__(256) void gemm_o(
    const ushort* __restrict__ A, const ushort* __restrict__ W,
    float* __restrict__ C)
{
    __shared__ ushort As[2 * 128 * 32];
    __shared__ ushort Bs[2 * 128 * 32];
    const int m0 = blockIdx.y * 128, n0 = blockIdx.x * 128;
    f32x4 acc[4][4];
    gemm_core_db(A, W, m0, n0, As, Bs, acc);

    const int lane = threadIdx.x & 63, w = threadIdx.x >> 6;
    const int quad = lane >> 4, l16 = lane & 15;
    const int row0 = m0 + (w & 1) * 64;
    const int col0 = n0 + (w >> 1) * 64;
#pragma unroll
    for (int mt = 0; mt < 4; ++mt)
#pragma unroll
        for (int nt = 0; nt < 4; ++nt)
#pragma unroll
            for (int r = 0; r < 4; ++r)
                C[(size_t)(row0 + mt * 16 + quad * 4 + r) * E_DIM
                  + col0 + nt * 16 + l16] = acc[mt][nt][r];
}

// ---------------------------------------------------------------------------
// Flash attention v6: SPLIT-K causal flash. Each (bh, qt) q-tile is handled
// by TWO blocks over disjoint jt halves. Fixed-max exp2 softmax (no running
// max) makes partials exactly additive: O = O_a + O_b, l = l_a + l_b.
// Blocks write un-normalized f32 O^T partials + partial l to workspace;
// attn_merge adds, normalizes, packs bf16.
// Grid 2048 ordered longest-qt-first (LPT) so the deep blocks start at t=0
// and short blocks backfill -> occupancy stays high, serial tail depth 16.
// ---------------------------------------------------------------------------
__global__ __launch_bounds__(256, 4) void flash_attn6(
    const ushort* __restrict__ Qg, const ushort* __restrict__ Kg,
    const ushort* __restrict__ Vt, float* __restrict__ Pbuf,
    float* __restrict__ Lbuf)
{
    __shared__ ushort Ks[2][64 * 64];   // 16 KB
    __shared__ ushort Vs[2][64 * 64];   // 16 KB

    const int tid  = threadIdx.x;
    const int lane = tid & 63, w = tid >> 6;
    const int quad = lane >> 4, l16 = lane & 15;

    const int pair  = blockIdx.x >> 1;          // 0..1023
    const int split = blockIdx.x & 1;
    const int bh = pair & 31;
    const int qt = 31 - (pair >> 5);            // longest work first (LPT)
    const int b = bh >> 4, h = bh & 15;

    const int ntile = qt + 1;
    const int hmid  = ntile >> 1;               // split0: [0,hmid) split1: [hmid,ntile)
    const int jt0 = split ? hmid  : 0;
    const int jt1 = split ? ntile : hmid;
    if (jt0 >= jt1) return;                     // qt=0 split0: empty (uniform)

    const int slot = (bh << 5) | qt;

    const ushort* Qbase = Qg + ((size_t)b * T_SEQ) * E_DIM + h * HS;
    const ushort* Kbase = Kg + ((size_t)b * T_SEQ) * E_DIM + h * HS;
    const ushort* Vbase = Vt + ((size_t)bh * HS) * T_SEQ;   // [d][t]

    const int rloc = lane >> 3;
    const int gswc = (lane & 7) ^ rloc;     // swizzled global chunk (staging)
    const int sw   = l16 & 7;               // frag-read xor factor

    // Q B-frags (16x16x32): B[n=q][k=d], lane n=l16 -> q row, k=quad*8+j
    bf16x8 aq[2];
#pragma unroll
    for (int ks = 0; ks < 2; ++ks)
        aq[ks] = *(const bf16x8*)(Qbase + (size_t)(qt * 64 + w * 16 + l16) * E_DIM
                                  + ks * 32 + quad * 8);

    const f32x4 zero = {0.f, 0.f, 0.f, 0.f};
    f32x4 o_acc[4];                     // O^T: lane col=q(l16), rows d=quad*4+r
#pragma unroll
    for (int dt = 0; dt < 4; ++dt) o_acc[dt] = zero;
    float l_acc = 0.f;                  // q is lane-fixed -> scalar l

    // initial stage of tile jt0 into buffer 0
#pragma unroll
    for (int i = 0; i < 2; ++i) {
        int cc = w * 2 + i, row = cc * 8 + rloc;
        load_lds16(Kbase + (size_t)(jt0 * 64 + row) * E_DIM + gswc * 8,
                   Ks[0] + cc * 512);
        load_lds16(Vbase + (size_t)row * T_SEQ + jt0 * 64 + gswc * 8,
                   Vs[0] + cc * 512);
    }

    const float M8 = 8.0f * LOG2E;   // fixed max in exp2 domain

    for (int jt = jt0; jt < jt1; ++jt) {
        const int buf = (jt - jt0) & 1;
        __syncthreads();   // drains vmcnt -> buf ready; syncs buffer reuse
        if (jt + 1 < jt1) {
#pragma unroll
            for (int i = 0; i < 2; ++i) {
                int cc = w * 2 + i, row = cc * 8 + rloc;
                load_lds16(Kbase + (size_t)(jt + 1) * 64 * E_DIM
                           + (size_t)row * E_DIM + gswc * 8, Ks[buf ^ 1] + cc * 512);
                load_lds16(Vbase + (size_t)row * T_SEQ + (jt + 1) * 64 + gswc * 8,
                           Vs[buf ^ 1] + cc * 512);
            }
        }

        // S^T = K Q^T: tiles over t (nt). A=K-frag (m=t), B=aq (n=q).
        f32x4 sa[4];
#pragma unroll
        for (int nt = 0; nt < 4; ++nt) sa[nt] = zero;
        __builtin_amdgcn_s_setprio(1);
#pragma unroll
        for (int ks = 0; ks < 2; ++ks) {
            int cp = ((ks * 4 + quad) ^ sw) * 8;
#pragma unroll
            for (int nt = 0; nt < 4; ++nt) {
                bf16x8 bk = *(const bf16x8*)(Ks[buf] + (nt * 16 + l16) * 64 + cp);
                sa[nt] = __builtin_amdgcn_mfma_f32_16x16x32_bf16(bk, aq[ks], sa[nt], 0, 0, 0);
            }
        }
        __builtin_amdgcn_s_setprio(0);

        if (jt == qt) {   // causal mask: t > q (only split1's last tile)
#pragma unroll
            for (int nt = 0; nt < 4; ++nt)
#pragma unroll
                for (int r = 0; r < 4; ++r)
                    if (nt * 16 + quad * 4 + r > w * 16 + l16) sa[nt][r] = -1e30f;
        }

        // p = exp2(s - 8*log2e); pairwise l accumulation (short dep chains)
        bf16x4 bp[4];
        float lp[4];
#pragma unroll
        for (int nt = 0; nt < 4; ++nt) {
            float p0 = __builtin_amdgcn_exp2f(sa[nt][0] - M8);
            float p1 = __builtin_amdgcn_exp2f(sa[nt][1] - M8);
            float p2 = __builtin_amdgcn_exp2f(sa[nt][2] - M8);
            float p3 = __builtin_amdgcn_exp2f(sa[nt][3] - M8);
            bp[nt][0] = (short)f2bf_trunc(p0);
            bp[nt][1] = (short)f2bf_trunc(p1);
            bp[nt][2] = (short)f2bf_trunc(p2);
            bp[nt][3] = (short)f2bf_trunc(p3);
            lp[nt] = (p0 + p1) + (p2 + p3);
        }
        l_acc += (lp[0] + lp[1]) + (lp[2] + lp[3]);

        // O^T += V^T @ P^T : A = V^T rows d (from Vs), B = bp[kt] (k = t)
        __builtin_amdgcn_s_setprio(1);
#pragma unroll
        for (int kt = 0; kt < 4; ++kt) {
            const int tt = kt * 16 + quad * 4;          // t of this k-slice
            const int ch = tt >> 3, el = tt & 7;
#pragma unroll
            for (int dt = 0; dt < 4; ++dt) {
                const int vd = dt * 16 + l16;
                bf16x4 va = *(const bf16x4*)(Vs[buf] + vd * 64
                                             + ((ch ^ (vd & 7)) << 3) + el);
                o_acc[dt] = mfma16(va, bp[kt], o_acc[dt]);
            }
        }
        __builtin_amdgcn_s_setprio(0);
    }

    // Epilogue: reduce l across quads, store RAW f32 partials (no divide).
    l_acc += __shfl_xor(l_acc, 16);
    l_acc += __shfl_xor(l_acc, 32);
    float* Po = Pbuf + (((size_t)split << 22) | ((size_t)slot << 12));
    const int q = w * 16 + l16;
#pragma unroll
    for (int dt = 0; dt < 4; ++dt)
        *(f32x4*)(Po + q * 64 + dt * 16 + quad * 4) = o_acc[dt];
    if (quad == 0) Lbuf[(split << 16) | (slot << 6) | q] = l_acc;
}

// ---------------------------------------------------------------------------
// Merge the two split-K partials: O = (P0 + P1) / (l0 + l1), pack bf16.
// Grid 1024 (one block per (bh,qt) slot), 256 threads.
// ---------------------------------------------------------------------------
__global__ __launch_bounds__(256) void attn_merge(
    const float* __restrict__ Pbuf, const float* __restrict__ Lbuf,
    ushort* __restrict__ O)
{
    const int slot = blockIdx.x;               // (bh<<5)|qt
    const int bh = slot >> 5, qt = slot & 31;
    const int b = bh >> 4, h = bh & 15;
    const int tid = threadIdx.x;
    const int dl = (tid & 15) * 4;             // d (4 consecutive floats)
    const int qh = tid >> 4;                   // q sub-row 0..15
    const bool has0 = (qt > 0);                // qt=0: split0 empty
    const float* P0 = Pbuf + ((size_t)slot << 12);
    const float* P1 = P0 + ((size_t)1 << 22);
#pragma unroll
    for (int j = 0; j < 4; ++j) {
        const int q = j * 16 + qh;
        float l = Lbuf[(1 << 16) | (slot << 6) | q];
        if (has0) l += Lbuf[(slot << 6) | q];
        const float inv = 1.0f / l;
        float4 c = *(const float4*)(P1 + q * 64 + dl);
        if (has0) {
            float4 a = *(const float4*)(P0 + q * 64 + dl);
            c.x += a.x; c.y += a.y; c.z += a.z; c.w += a.w;
        }
        ushort4 pk = make_ushort4(f2bf(c.x * inv), f2bf(c.y * inv),
                                  f2bf(c.z * inv), f2bf(c.w * inv));
        *(ushort4*)(O + ((size_t)(b * T_SEQ + qt * 64 + q)) * E_DIM
                    + h * HS + dl) = pk;
    }
}

// ---------------------------------------------------------------------------
extern "C" void kernel_launch(void* const* d_in, const int* in_sizes, int n_in,
                              void* d_out, int out_size, void* d_ws, size_t ws_size,
                              hipStream_t stream) {
    const float* x     = (const float*)d_in[0];
    const float* Wk    = (const float*)d_in[1];
    const float* Wq    = (const float*)d_in[2];
    const float* Wv    = (const float*)d_in[3];
    const float* Wu    = (const float*)d_in[4];
    const float* kln_w = (const float*)d_in[5];
    const float* kln_b = (const float*)d_in[6];
    const float* qln_w = (const float*)d_in[7];
    const float* qln_b = (const float*)d_in[8];
    float* out = (float*)d_out;

    const size_t NE = (size_t)M_ROWS * E_DIM;   // 4M elems
    const size_t NW = (size_t)E_DIM * E_DIM;    // 1M elems
    ushort* xb  = (ushort*)d_ws;                // 4M
    ushort* Wkb = xb  + NE;                     // 1M each
    ushort* Wqb = Wkb + NW;
    ushort* Wvb = Wqb + NW;
    ushort* Wub = Wvb + NW;
    ushort* Kb  = Wub + NW;                     // 4M
    ushort* Qb  = Kb  + NE;                     // 4M
    ushort* Vt  = Qb  + NE;                     // 4M, [bh][d][t]
    ushort* Ob  = Vt  + NE;                     // 4M
    float*  Pbuf = (float*)(Ob + NE);           // 2 x 1024 x 4096 f32 = 32 MB
    float*  Lbuf = Pbuf + ((size_t)2 << 22);    // 2 x 65536 f32 = 512 KB

    // 1) fp32 -> bf16
    cvt_all<<<8192, 256, 0, stream>>>(x, Wk, Wq, Wv, Wu, xb, Wkb, Wqb, Wvb, Wub);

    // 2) K/Q/V projections (128x128 z-grid, dbuf) with fused LN + V-transpose
    gemm_qkv<<<dim3(E_DIM / 128, M_ROWS / 128, 3), 256, 0, stream>>>(
        xb, Wkb, Wqb, Wvb, Kb, Qb, Vt, kln_w, kln_b, qln_w, qln_b);

    // 3) Causal flash attention, split-K x2 (LPT order) + merge
    flash_attn6<<<2048, 256, 0, stream>>>(Qb, Kb, Vt, Pbuf, Lbuf);
    attn_merge<<<1024, 256, 0, stream>>>(Pbuf, Lbuf, Ob);

    // 4) Output projection (128x128, dbuf) -> fp32 out
    gemm_o<<<dim3(E_DIM / 128, M_ROWS / 128), 256, 0, stream>>>(Ob, Wub, out);
}

// Round 2
// 185.051 us; speedup vs baseline: 1.0065x; 1.0065x over previous
//
#include <hip/hip_runtime.h>
#include <math.h>

// Problem constants (B=2, T=2048, E=1024, H=16, S=64)
#define T_SEQ 2048
#define E_DIM 1024
#define NH    16
#define HS    64
#define NB    2
#define M_ROWS 4096

typedef __attribute__((ext_vector_type(8))) short bf16x8;
typedef __attribute__((ext_vector_type(4))) short bf16x4;
typedef __attribute__((ext_vector_type(4))) float f32x4;

#define AS1 __attribute__((address_space(1)))
#define AS3 __attribute__((address_space(3)))

#define LOG2E 1.4426950408889634f

// 16x16x16 bf16 MFMA (K=16): B-operand k-index (quad*4+j) matches the
// C-layout row index (quad*4+r) — QK^T's S^T accumulator feeds PV directly.
__device__ __forceinline__ f32x4 mfma16(bf16x4 a, bf16x4 b, f32x4 c) {
    return __builtin_amdgcn_mfma_f32_16x16x16bf16_1k(a, b, c, 0, 0, 0);
}

__device__ __forceinline__ ushort f2bf(float f) {
    union { float f; unsigned u; } c; c.f = f;
    unsigned r = c.u + 0x7fffu + ((c.u >> 16) & 1u);
    return (ushort)(r >> 16);
}
__device__ __forceinline__ ushort f2bf_trunc(float f) {
    union { float f; unsigned u; } c; c.f = f;
    return (ushort)(c.u >> 16);
}

__device__ __forceinline__ void load_lds16(const ushort* g, ushort* l) {
    // 16B per lane, LDS dest = wave-uniform base + lane*16 (HW behavior)
    __builtin_amdgcn_global_load_lds((const AS1 unsigned int*)g,
                                     (AS3 unsigned int*)l, 16, 0, 0);
}

// ---------------------------------------------------------------------------
// fp32 -> bf16 conversion for x and the four weight matrices.
// Wk/Wq/Wv land contiguously -> packed Wqkv [3072][1024] for the fused GEMM.
// ---------------------------------------------------------------------------
__global__ __launch_bounds__(256) void cvt_all(
    const float* __restrict__ x,  const float* __restrict__ Wk,
    const float* __restrict__ Wq, const float* __restrict__ Wv,
    const float* __restrict__ Wu,
    ushort* __restrict__ xb,  ushort* __restrict__ Wkb,
    ushort* __restrict__ Wqb, ushort* __restrict__ Wvb,
    ushort* __restrict__ Wub)
{
    int i4 = blockIdx.x * 256 + threadIdx.x;   // 0 .. 2M-1 (float4 units)
    int region = i4 >> 18;
    const float* src; ushort* dst; int off;
    if      (region < 4)  { src = x;  dst = xb;  off = i4; }
    else if (region == 4) { src = Wk; dst = Wkb; off = i4 - (4 << 18); }
    else if (region == 5) { src = Wq; dst = Wqb; off = i4 - (5 << 18); }
    else if (region == 6) { src = Wv; dst = Wvb; off = i4 - (6 << 18); }
    else                  { src = Wu; dst = Wub; off = i4 - (7 << 18); }
    float4 v = *(const float4*)(src + (size_t)off * 4);
    ushort4 o; o.x = f2bf(v.x); o.y = f2bf(v.y); o.z = f2bf(v.z); o.w = f2bf(v.w);
    *(ushort4*)(dst + (size_t)off * 4) = o;
}

// ---------------------------------------------------------------------------
// bf16 MFMA GEMM core, 128x128 tile, BK=32, 4 waves (used by gemm_o).
// ---------------------------------------------------------------------------
__device__ __forceinline__ void gemm_core_db(
    const ushort* __restrict__ A, const ushort* __restrict__ W,
    int m0, int n0, ushort* As, ushort* Bs, f32x4 acc[4][4])
{
    const int tid  = threadIdx.x;
    const int lane = tid & 63, w = tid >> 6;
    const int quad = lane >> 4, l16 = lane & 15;
    const int wm = w & 1, wn = w >> 1;

    const int rl   = lane >> 2;                       // row-in-chunk 0..15
    const int gsw  = (lane & 3) ^ ((lane >> 3) & 3);  // swizzled global chunk
    const int fsw  = (l16 >> 1) & 3;                  // frag-read xor factor

    const f32x4 zero = {0.f, 0.f, 0.f, 0.f};
#pragma unroll
    for (int mt = 0; mt < 4; ++mt)
#pragma unroll
        for (int nt = 0; nt < 4; ++nt) acc[mt][nt] = zero;

    // initial stage into buffer 0
#pragma unroll
    for (int i = 0; i < 2; ++i) {
        int c = i * 4 + w;                 // chunk 0..7 (16 rows x 64B)
        int row = c * 16 + rl;
        load_lds16(A + (size_t)(m0 + row) * E_DIM + gsw * 8, As + c * 512);
        load_lds16(W + (size_t)(n0 + row) * E_DIM + gsw * 8, Bs + c * 512);
    }

    for (int k0 = 0; k0 < E_DIM; k0 += 32) {
        const int buf = (k0 >> 5) & 1;
        ushort* Ab = As + buf * 4096;
        ushort* Bb = Bs + buf * 4096;
        __syncthreads();   // own-wave vmcnt drained -> buf ready; syncs reuse
        if (k0 + 32 < E_DIM) {
            ushort* An = As + (buf ^ 1) * 4096;
            ushort* Bn = Bs + (buf ^ 1) * 4096;
#pragma unroll
            for (int i = 0; i < 2; ++i) {
                int c = i * 4 + w;
                int row = c * 16 + rl;
                load_lds16(A + (size_t)(m0 + row) * E_DIM + k0 + 32 + gsw * 8,
                           An + c * 512);
                load_lds16(W + (size_t)(n0 + row) * E_DIM + k0 + 32 + gsw * 8,
                           Bn + c * 512);
            }
        }
        bf16x8 af[4], bfr[4];
#pragma unroll
        for (int mt = 0; mt < 4; ++mt)
            af[mt] = *(const bf16x8*)(Ab + (wm * 64 + mt * 16 + l16) * 32
                                      + ((quad ^ fsw) * 8));
#pragma unroll
        for (int nt = 0; nt < 4; ++nt)
            bfr[nt] = *(const bf16x8*)(Bb + (wn * 64 + nt * 16 + l16) * 32
                                       + ((quad ^ fsw) * 8));
#pragma unroll
        for (int mt = 0; mt < 4; ++mt)
#pragma unroll
            for (int nt = 0; nt < 4; ++nt)
                acc[mt][nt] = __builtin_amdgcn_mfma_f32_16x16x32_bf16(
                    af[mt], bfr[nt], acc[mt][nt], 0, 0, 0);
    }
}

// ---------------------------------------------------------------------------
// Fused QKV GEMM, 256x256 tile, BK=64, 8 waves (2M x 4N), 128 KiB dynamic LDS.
// One barrier per K-tile; 64 MFMA/wave/barrier -> staging loads (front-issued
// right after the barrier) get a full tile of latency cover before the next
// barrier's implicit vmcnt(0) drain. Swizzle pair identical to flash staging:
// linear gload_lds dest + source chunk (lane&7)^rloc, read chunk c^(l16&7).
// N = 3072 packed [Wk;Wq;Wv]; epilogue by n-region: LN-K / LN-Q / V-transpose.
// Grid 192 (16M x 12N), bijective XCD swizzle, 1 block/CU.
// ---------------------------------------------------------------------------
__global__ __launch_bounds__(512, 2) void gemm_qkv256(
    const ushort* __restrict__ A, const ushort* __restrict__ Wqkv,
    ushort* __restrict__ Kb, ushort* __restrict__ Qb, ushort* __restrict__ Vt,
    const float* __restrict__ kw, const float* __restrict__ kbias,
    const float* __restrict__ qw, const float* __restrict__ qbias)
{
    extern __shared__ ushort smem[];
    ushort* As = smem;                 // 2 x 256 x 64 ushort = 64 KiB
    ushort* Bs = smem + 2 * 256 * 64;  // 2 x 256 x 64 ushort = 64 KiB

    const int tid  = threadIdx.x;
    const int lane = tid & 63, w = tid >> 6;       // 8 waves
    const int quad = lane >> 4, l16 = lane & 15;
    const int wm = w & 1, wn = w >> 1;             // 2 x 4 wave grid

    // bijective XCD swizzle (192 % 8 == 0): column-major block walk
    const int lid = blockIdx.x;                    // 0..191
    const int swz = (lid & 7) * 24 + (lid >> 3);
    const int m0  = (swz & 15) * 256;
    const int n0  = (swz >> 4) * 256;              // 0..2816 over packed N=3072

    const int rloc = lane >> 3;                    // 0..7 (row within 8-row grp)
    const int gswc = (lane & 7) ^ rloc;            // swizzled source chunk
    const int sw   = l16 & 7;                      // frag-read xor factor

    f32x4 acc[8][4];
    const f32x4 zero = {0.f, 0.f, 0.f, 0.f};
#pragma unroll
    for (int mt = 0; mt < 8; ++mt)
#pragma unroll
        for (int nt = 0; nt < 4; ++nt) acc[mt][nt] = zero;

    // per-lane staging bases (wave w stages rows [w*32, w*32+32) of each tile)
    const ushort* Ag = A    + (size_t)(m0 + w * 32 + rloc) * E_DIM + gswc * 8;
    const ushort* Bg = Wqkv + (size_t)(n0 + w * 32 + rloc) * E_DIM + gswc * 8;

    // stage tile 0 into buffer 0
#pragma unroll
    for (int i = 0; i < 4; ++i) {
        load_lds16(Ag + (size_t)i * 8 * E_DIM, As + (w * 32 + i * 8) * 64);
        load_lds16(Bg + (size_t)i * 8 * E_DIM, Bs + (w * 32 + i * 8) * 64);
    }

    for (int t = 0; t < 16; ++t) {
        const int buf = t & 1;
        ushort* Ab = As + buf * 16384;
        ushort* Bb = Bs + buf * 16384;
        __syncthreads();   // implicit vmcnt(0): buf ready; buf^1 reads done
        if (t + 1 < 16) {  // front-issue next tile's 8 loads -> full-tile cover
            ushort* An = As + (buf ^ 1) * 16384;
            ushort* Bn = Bs + (buf ^ 1) * 16384;
            const int ko = (t + 1) * 64;
#pragma unroll
            for (int i = 0; i < 4; ++i) {
                load_lds16(Ag + (size_t)i * 8 * E_DIM + ko,
                           An + (w * 32 + i * 8) * 64);
                load_lds16(Bg + (size_t)i * 8 * E_DIM + ko,
                           Bn + (w * 32 + i * 8) * 64);
            }
        }
        bf16x8 af[4], bfr[4];
#pragma unroll
        for (int ks = 0; ks < 2; ++ks) {
            const int cp = (((ks * 4 + quad) ^ sw)) * 8;
#pragma unroll
            for (int nt = 0; nt < 4; ++nt)
                bfr[nt] = *(const bf16x8*)(Bb + (wn * 64 + nt * 16 + l16) * 64 + cp);
#pragma unroll
            for (int h2 = 0; h2 < 2; ++h2) {
#pragma unroll
                for (int i = 0; i < 4; ++i)
                    af[i] = *(const bf16x8*)(Ab + (wm * 128 + (h2 * 4 + i) * 16 + l16) * 64 + cp);
                __builtin_amdgcn_s_setprio(1);
#pragma unroll
                for (int i = 0; i < 4; ++i)
#pragma unroll
                    for (int nt = 0; nt < 4; ++nt)
                        acc[h2 * 4 + i][nt] = __builtin_amdgcn_mfma_f32_16x16x32_bf16(
                            af[i], bfr[nt], acc[h2 * 4 + i][nt], 0, 0, 0);
                __builtin_amdgcn_s_setprio(0);
            }
        }
    }

    // ---- epilogue -----------------------------------------------------------
    const int z    = n0 >> 10;           // 0:K 1:Q 2:V (blocks never straddle)
    const int ncol = n0 & 1023;
    const int col0 = ncol + wn * 64;     // 64-aligned -> exactly one head
    const int row0 = m0 + wm * 128;

    if (z < 2) {
        ushort* C = z ? Qb : Kb;
        const float* lw = z ? qw : kw;
        const float* lb = z ? qbias : kbias;
        const float scale = z ? (0.125f * LOG2E) : 1.0f;
        float wv[4], bv_[4];
#pragma unroll
        for (int nt = 0; nt < 4; ++nt) {
            wv[nt]  = lw[nt * 16 + l16];
            bv_[nt] = lb[nt * 16 + l16];
        }
#pragma unroll
        for (int mt = 0; mt < 8; ++mt)
#pragma unroll
            for (int r = 0; r < 4; ++r) {
                float v[4], d[4];
#pragma unroll
                for (int nt = 0; nt < 4; ++nt) v[nt] = acc[mt][nt][r];
                float s = v[0] + v[1] + v[2] + v[3];
                s += __shfl_xor(s, 1); s += __shfl_xor(s, 2);
                s += __shfl_xor(s, 4); s += __shfl_xor(s, 8);
                float mu = s * (1.0f / 64.0f);
                float q2 = 0.f;
#pragma unroll
                for (int nt = 0; nt < 4; ++nt) { d[nt] = v[nt] - mu; q2 += d[nt] * d[nt]; }
                q2 += __shfl_xor(q2, 1); q2 += __shfl_xor(q2, 2);
                q2 += __shfl_xor(q2, 4); q2 += __shfl_xor(q2, 8);
                float rin = rsqrtf(q2 * (1.0f / 64.0f) + 1e-5f);
                int row = row0 + mt * 16 + quad * 4 + r;
#pragma unroll
                for (int nt = 0; nt < 4; ++nt)
                    C[(size_t)row * E_DIM + col0 + nt * 16 + l16] =
                        f2bf((d[nt] * rin * wv[nt] + bv_[nt]) * scale);
            }
    } else {
        // V: transposed store Vt[(b*NH+h)*64 + d][t]
        const int bidx = m0 >> 11;
        const int hh   = col0 >> 6;
        const int t0   = (m0 & 2047) + wm * 128;
#pragma unroll
        for (int mt = 0; mt < 8; ++mt)
#pragma unroll
            for (int nt = 0; nt < 4; ++nt) {
                ushort4 pk = make_ushort4(f2bf(acc[mt][nt][0]), f2bf(acc[mt][nt][1]),
                                          f2bf(acc[mt][nt][2]), f2bf(acc[mt][nt][3]));
                size_t off = ((size_t)(bidx * NH + hh) * 64 + nt * 16 + l16) * T_SEQ
                             + t0 + mt * 16 + quad * 4;
                *(ushort4*)(Vt + off) = pk;
            }
    }
}

// ---------------------------------------------------------------------------
// Output GEMM: 128x128 tiles (grid 8x32 = 256 blocks), dbuf core, fp32 store.
// ---------------------------------------------------------------------------
__global__ __launch_bounds__(256) void gemm_o(
    const ushort* __restrict__ A, const ushort* __restrict__ W,
    float* __restrict__ C)
{
    __shared__ ushort As[2 * 128 * 32];
    __shared__ ushort Bs[2 * 128 * 32];
    const int m0 = blockIdx.y * 128, n0 = blockIdx.x * 128;
    f32x4 acc[4][4];
    gemm_core_db(A, W, m0, n0, As, Bs, acc);

    const int lane = threadIdx.x & 63, w = threadIdx.x >> 6;
    const int quad = lane >> 4, l16 = lane & 15;
    const int row0 = m0 + (w & 1) * 64;
    const int col0 = n0 + (w >> 1) * 64;
#pragma unroll
    for (int mt = 0; mt < 4; ++mt)
#pragma unroll
        for (int nt = 0; nt < 4; ++nt)
#pragma unroll
            for (int r = 0; r < 4; ++r)
                C[(size_t)(row0 + mt * 16 + quad * 4 + r) * E_DIM
                  + col0 + nt * 16 + l16] = acc[mt][nt][r];
}

// ---------------------------------------------------------------------------
// Flash attention v6: SPLIT-K causal flash (fixed-max exp2 softmax => exact
// additive partials). Un-normalized f32 O^T partials + partial l -> workspace;
// attn_merge adds, normalizes, packs bf16. Grid 2048 LPT-ordered.
// ---------------------------------------------------------------------------
__global__ __launch_bounds__(256, 4) void flash_attn6(
    const ushort* __restrict__ Qg, const ushort* __restrict__ Kg,
    const ushort* __restrict__ Vt, float* __restrict__ Pbuf,
    float* __restrict__ Lbuf)
{
    __shared__ ushort Ks[2][64 * 64];   // 16 KB
    __shared__ ushort Vs[2][64 * 64];   // 16 KB

    const int tid  = threadIdx.x;
    const int lane = tid & 63, w = tid >> 6;
    const int quad = lane >> 4, l16 = lane & 15;

    const int pair  = blockIdx.x >> 1;          // 0..1023
    const int split = blockIdx.x & 1;
    const int bh = pair & 31;
    const int qt = 31 - (pair >> 5);            // longest work first (LPT)
    const int b = bh >> 4, h = bh & 15;

    const int ntile = qt + 1;
    const int hmid  = ntile >> 1;               // split0: [0,hmid) split1: [hmid,ntile)
    const int jt0 = split ? hmid  : 0;
    const int jt1 = split ? ntile : hmid;
    if (jt0 >= jt1) return;                     // qt=0 split0: empty (uniform)

    const int slot = (bh << 5) | qt;

    const ushort* Qbase = Qg + ((size_t)b * T_SEQ) * E_DIM + h * HS;
    const ushort* Kbase = Kg + ((size_t)b * T_SEQ) * E_DIM + h * HS;
    const ushort* Vbase = Vt + ((size_t)bh * HS) * T_SEQ;   // [d][t]

    const int rloc = lane >> 3;
    const int gswc = (lane & 7) ^ rloc;     // swizzled global chunk (staging)
    const int sw   = l16 & 7;               // frag-read xor factor

    // Q B-frags (16x16x32): B[n=q][k=d], lane n=l16 -> q row, k=quad*8+j
    bf16x8 aq[2];
#pragma unroll
    for (int ks = 0; ks < 2; ++ks)
        aq[ks] = *(const bf16x8*)(Qbase + (size_t)(qt * 64 + w * 16 + l16) * E_DIM
                                  + ks * 32 + quad * 8);

    const f32x4 zero = {0.f, 0.f, 0.f, 0.f};
    f32x4 o_acc[4];                     // O^T: lane col=q(l16), rows d=quad*4+r
#pragma unroll
    for (int dt = 0; dt < 4; ++dt) o_acc[dt] = zero;
    float l_acc = 0.f;                  // q is lane-fixed -> scalar l

    // initial stage of tile jt0 into buffer 0
#pragma unroll
    for (int i = 0; i < 2; ++i) {
        int cc = w * 2 + i, row = cc * 8 + rloc;
        load_lds16(Kbase + (size_t)(jt0 * 64 + row) * E_DIM + gswc * 8,
                   Ks[0] + cc * 512);
        load_lds16(Vbase + (size_t)row * T_SEQ + jt0 * 64 + gswc * 8,
                   Vs[0] + cc * 512);
    }

    const float M8 = 8.0f * LOG2E;   // fixed max in exp2 domain

    for (int jt = jt0; jt < jt1; ++jt) {
        const int buf = (jt - jt0) & 1;
        __syncthreads();   // drains vmcnt -> buf ready; syncs buffer reuse
        if (jt + 1 < jt1) {
#pragma unroll
            for (int i = 0; i < 2; ++i) {
                int cc = w * 2 + i, row = cc * 8 + rloc;
                load_lds16(Kbase + (size_t)(jt + 1) * 64 * E_DIM
                           + (size_t)row * E_DIM + gswc * 8, Ks[buf ^ 1] + cc * 512);
                load_lds16(Vbase + (size_t)row * T_SEQ + (jt + 1) * 64 + gswc * 8,
                           Vs[buf ^ 1] + cc * 512);
            }
        }

        // S^T = K Q^T: tiles over t (nt). A=K-frag (m=t), B=aq (n=q).
        f32x4 sa[4];
#pragma unroll
        for (int nt = 0; nt < 4; ++nt) sa[nt] = zero;
        __builtin_amdgcn_s_setprio(1);
#pragma unroll
        for (int ks = 0; ks < 2; ++ks) {
            int cp = ((ks * 4 + quad) ^ sw) * 8;
#pragma unroll
            for (int nt = 0; nt < 4; ++nt) {
                bf16x8 bk = *(const bf16x8*)(Ks[buf] + (nt * 16 + l16) * 64 + cp);
                sa[nt] = __builtin_amdgcn_mfma_f32_16x16x32_bf16(bk, aq[ks], sa[nt], 0, 0, 0);
            }
        }
        __builtin_amdgcn_s_setprio(0);

        if (jt == qt) {   // causal mask: t > q (only split1's last tile)
#pragma unroll
            for (int nt = 0; nt < 4; ++nt)
#pragma unroll
                for (int r = 0; r < 4; ++r)
                    if (nt * 16 + quad * 4 + r > w * 16 + l16) sa[nt][r] = -1e30f;
        }

        // p = exp2(s - 8*log2e); pairwise l accumulation (short dep chains)
        bf16x4 bp[4];
        float lp[4];
#pragma unroll
        for (int nt = 0; nt < 4; ++nt) {
            float p0 = __builtin_amdgcn_exp2f(sa[nt][0] - M8);
            float p1 = __builtin_amdgcn_exp2f(sa[nt][1] - M8);
            float p2 = __builtin_amdgcn_exp2f(sa[nt][2] - M8);
            float p3 = __builtin_amdgcn_exp2f(sa[nt][3] - M8);
            bp[nt][0] = (short)f2bf_trunc(p0);
            bp[nt][1] = (short)f2bf_trunc(p1);
            bp[nt][2] = (short)f2bf_trunc(p2);
            bp[nt][3] = (short)f2bf_trunc(p3);
            lp[nt] = (p0 + p1) + (p2 + p3);
        }
        l_acc += (lp[0] + lp[1]) + (lp[2] + lp[3]);

        // O^T += V^T @ P^T : A = V^T rows d (from Vs), B = bp[kt] (k = t)
        __builtin_amdgcn_s_setprio(1);
#pragma unroll
        for (int kt = 0; kt < 4; ++kt) {
            const int tt = kt * 16 + quad * 4;          // t of this k-slice
            const int ch = tt >> 3, el = tt & 7;
#pragma unroll
            for (int dt = 0; dt < 4; ++dt) {
                const int vd = dt * 16 + l16;
                bf16x4 va = *(const bf16x4*)(Vs[buf] + vd * 64
                                             + ((ch ^ (vd & 7)) << 3) + el);
                o_acc[dt] = mfma16(va, bp[kt], o_acc[dt]);
            }
        }
        __builtin_amdgcn_s_setprio(0);
    }

    // Epilogue: reduce l across quads, store RAW f32 partials (no divide).
    l_acc += __shfl_xor(l_acc, 16);
    l_acc += __shfl_xor(l_acc, 32);
    float* Po = Pbuf + (((size_t)split << 22) | ((size_t)slot << 12));
    const int q = w * 16 + l16;
#pragma unroll
    for (int dt = 0; dt < 4; ++dt)
        *(f32x4*)(Po + q * 64 + dt * 16 + quad * 4) = o_acc[dt];
    if (quad == 0) Lbuf[(split << 16) | (slot << 6) | q] = l_acc;
}

// ---------------------------------------------------------------------------
// Merge the two split-K partials: O = (P0 + P1) / (l0 + l1), pack bf16.
// ---------------------------------------------------------------------------
__global__ __launch_bounds__(256) void attn_merge(
    const float* __restrict__ Pbuf, const float* __restrict__ Lbuf,
    ushort* __restrict__ O)
{
    const int slot = blockIdx.x;               // (bh<<5)|qt
    const int bh = slot >> 5, qt = slot & 31;
    const int b = bh >> 4, h = bh & 15;
    const int tid = threadIdx.x;
    const int dl = (tid & 15) * 4;             // d (4 consecutive floats)
    const int qh = tid >> 4;                   // q sub-row 0..15
    const bool has0 = (qt > 0);                // qt=0: split0 empty
    const float* P0 = Pbuf + ((size_t)slot << 12);
    const float* P1 = P0 + ((size_t)1 << 22);
#pragma unroll
    for (int j = 0; j < 4; ++j) {
        const int q = j * 16 + qh;
        float l = Lbuf[(1 << 16) | (slot << 6) | q];
        if (has0) l += Lbuf[(slot << 6) | q];
        const float inv = 1.0f / l;
        float4 c = *(const float4*)(P1 + q * 64 + dl);
        if (has0) {
            float4 a = *(const float4*)(P0 + q * 64 + dl);
            c.x += a.x; c.y += a.y; c.z += a.z; c.w += a.w;
        }
        ushort4 pk = make_ushort4(f2bf(c.x * inv), f2bf(c.y * inv),
                                  f2bf(c.z * inv), f2bf(c.w * inv));
        *(ushort4*)(O + ((size_t)(b * T_SEQ + qt * 64 + q)) * E_DIM
                    + h * HS + dl) = pk;
    }
}

// ---------------------------------------------------------------------------
extern "C" void kernel_launch(void* const* d_in, const int* in_sizes, int n_in,
                              void* d_out, int out_size, void* d_ws, size_t ws_size,
                              hipStream_t stream) {
    const float* x     = (const float*)d_in[0];
    const float* Wk    = (const float*)d_in[1];
    const float* Wq    = (const float*)d_in[2];
    const float* Wv    = (const float*)d_in[3];
    const float* Wu    = (const float*)d_in[4];
    const float* kln_w = (const float*)d_in[5];
    const float* kln_b = (const float*)d_in[6];
    const float* qln_w = (const float*)d_in[7];
    const float* qln_b = (const float*)d_in[8];
    float* out = (float*)d_out;

    const size_t NE = (size_t)M_ROWS * E_DIM;   // 4M elems
    const size_t NW = (size_t)E_DIM * E_DIM;    // 1M elems
    ushort* xb  = (ushort*)d_ws;                // 4M
    ushort* Wkb = xb  + NE;                     // 1M each; Wk;Wq;Wv contiguous
    ushort* Wqb = Wkb + NW;                     //   -> packed Wqkv [3072][1024]
    ushort* Wvb = Wqb + NW;
    ushort* Wub = Wvb + NW;
    ushort* Kb  = Wub + NW;                     // 4M
    ushort* Qb  = Kb  + NE;                     // 4M
    ushort* Vt  = Qb  + NE;                     // 4M, [bh][d][t]
    ushort* Ob  = Vt  + NE;                     // 4M
    float*  Pbuf = (float*)(Ob + NE);           // 2 x 1024 x 4096 f32 = 32 MB
    float*  Lbuf = Pbuf + ((size_t)2 << 22);    // 2 x 65536 f32 = 512 KB

    // one-time: allow 128 KiB dynamic LDS for the 256^2 core
    static int attr_done = 0;
    if (!attr_done) {
        hipFuncSetAttribute(reinterpret_cast<const void*>(gemm_qkv256),
                            hipFuncAttributeMaxDynamicSharedMemorySize, 131072);
        attr_done = 1;
    }

    // 1) fp32 -> bf16 (weights land packed: [Wk;Wq;Wv] = Wqkv)
    cvt_all<<<8192, 256, 0, stream>>>(x, Wk, Wq, Wv, Wu, xb, Wkb, Wqb, Wvb, Wub);

    // 2) Fused QKV projection (256^2, 8-wave, BK=64) + LN / V-transpose
    gemm_qkv256<<<192, 512, 131072, stream>>>(
        xb, Wkb, Kb, Qb, Vt, kln_w, kln_b, qln_w, qln_b);

    // 3) Causal flash attention, split-K x2 (LPT order) + merge
    flash_attn6<<<2048, 256, 0, stream>>>(Qb, Kb, Vt, Pbuf, Lbuf);
    attn_merge<<<1024, 256, 0, stream>>>(Pbuf, Lbuf, Ob);

    // 4) Output projection (128x128, dbuf) -> fp32 out
    gemm_o<<<dim3(E_DIM / 128, M_ROWS / 128), 256, 0, stream>>>(Ob, Wub, out);
}